// Round 2
// baseline (155.648 us; speedup 1.0000x reference)
//
#include <hip/hip_runtime.h>
#include <hip/hip_cooperative_groups.h>

namespace cg = cooperative_groups;

// Single cooperative dispatch, no workspace initialization needed (re-poison safe):
//   phase 1: NBLK blocks write partial (loss, trivial) pairs to ws[2*b], ws[2*b+1]
//   grid.sync()
//   phase 2: block 0 recounts pos/neg from target, reduces partials, writes out[0]
//
// ws usage: NBLK*2 floats (NBLK = ceil(n/256) * NJ = 512 at n=8192) -> 4 KB.

#define NJ 16   // j-chunks per i-tile; grid = ceil(n/256) * NJ blocks

__global__ __launch_bounds__(256) void one_kernel(
        const float* __restrict__ pred,
        const int* __restrict__ target,
        float* __restrict__ ws,
        float* __restrict__ out, int n) {
    __shared__ __align__(16) float s_pj[256];
    int tid = threadIdx.x;
    int b   = blockIdx.x;
    int ib  = b >> 4;        // i-tile   (NJ == 16)
    int jc  = b & (NJ - 1);  // j-chunk
    int i   = ib * 256 + tid;

    // Branch-free pair semantics: non-pos/invalid i -> -1e30 (contributes 0),
    // non-neg/invalid j -> +1e30 (contributes 0). -1e30 - 1e30 = -2e30, no inf.
    float pi = -1e30f;
    float triv = 0.0f;
    if (i < n) {
        float p = pred[i];
        if (target[i] == 1) pi = p;
        if (jc == 0) triv = 1.0f / (p * p + 1e-5f);  // each i counted once
    }

    int jchunk = (n + NJ - 1) / NJ;
    int j0 = jc * jchunk;
    int j1 = min(j0 + jchunk, n);

    float a0 = 0.0f, a1 = 0.0f, a2 = 0.0f, a3 = 0.0f;
    for (int jb = j0; jb < j1; jb += 256) {
        int j = jb + tid;
        float pj = 1e30f;
        if (j < j1 && target[j] == 0) pj = pred[j];
        __syncthreads();            // protect previous iteration's readers
        s_pj[tid] = pj;
        __syncthreads();
        int cnt = min(256, j1 - jb);
        int c4  = cnt >> 2;
        const float4* s4 = (const float4*)s_pj;
        #pragma unroll 8
        for (int k = 0; k < c4; ++k) {
            float4 v = s4[k];       // LDS broadcast read, 16B per ds_read
            a0 += fmaxf(pi - v.x, 0.0f);
            a1 += fmaxf(pi - v.y, 0.0f);
            a2 += fmaxf(pi - v.z, 0.0f);
            a3 += fmaxf(pi - v.w, 0.0f);
        }
        for (int k = c4 << 2; k < cnt; ++k)
            a0 += fmaxf(pi - s_pj[k], 0.0f);
    }
    float acc = (a0 + a1) + (a2 + a3);

    // block reduce (wave64 shuffle + LDS across 4 waves)
    for (int off = 32; off > 0; off >>= 1) {
        acc  += __shfl_down(acc,  off, 64);
        triv += __shfl_down(triv, off, 64);
    }
    __shared__ float s_a[4], s_t[4];
    int lane = tid & 63, wave = tid >> 6;
    if (lane == 0) { s_a[wave] = acc; s_t[wave] = triv; }
    __syncthreads();
    if (tid == 0) {
        ws[2 * b]     = s_a[0] + s_a[1] + s_a[2] + s_a[3];  // partial loss
        ws[2 * b + 1] = s_t[0] + s_t[1] + s_t[2] + s_t[3];  // partial trivial
    }

    // cross-XCD visibility: release before, acquire after (Guideline 16)
    __threadfence();
    cg::this_grid().sync();
    __threadfence();

    if (b != 0) return;

    // ---- phase 2: block 0 only ----
    int nblk = gridDim.x;
    int pos = 0, neg = 0;
    for (int k = tid; k < n; k += 256) {   // 32 KB, L2-resident
        int t = target[k];
        pos += (t == 1);
        neg += (t == 0);
    }
    float loss = 0.0f, tr = 0.0f;
    for (int k = tid; k < nblk; k += 256) {
        loss += ws[2 * k];
        tr   += ws[2 * k + 1];
    }

    for (int off = 32; off > 0; off >>= 1) {
        loss += __shfl_down(loss, off, 64);
        tr   += __shfl_down(tr,   off, 64);
        pos  += __shfl_down(pos,  off, 64);
        neg  += __shfl_down(neg,  off, 64);
    }
    __shared__ float s_l[4], s_t2[4];
    __shared__ int   s_p[4], s_n[4];
    if (lane == 0) { s_l[wave] = loss; s_t2[wave] = tr; s_p[wave] = pos; s_n[wave] = neg; }
    __syncthreads();
    if (tid == 0) {
        float L = s_l[0] + s_l[1] + s_l[2] + s_l[3];
        float T = s_t2[0] + s_t2[1] + s_t2[2] + s_t2[3];
        float P = (float)(s_p[0] + s_p[1] + s_p[2] + s_p[3]);
        float G = (float)(s_n[0] + s_n[1] + s_n[2] + s_n[3]);
        out[0] = T / (float)n + L / (P * G);
    }
}

extern "C" void kernel_launch(void* const* d_in, const int* in_sizes, int n_in,
                              void* d_out, int out_size, void* d_ws, size_t ws_size,
                              hipStream_t stream) {
    const float* pred   = (const float*)d_in[0];
    const int*   target = (const int*)d_in[1];
    int n = in_sizes[0];
    float* ws = (float*)d_ws;
    float* outp = (float*)d_out;

    int nti  = (n + 255) / 256;   // i-tiles (32 at n=8192)
    int nblk = nti * NJ;          // 512 blocks (2 per CU -> co-resident)

    void* args[] = { (void*)&pred, (void*)&target, (void*)&ws, (void*)&outp, (void*)&n };
    hipLaunchCooperativeKernel((const void*)one_kernel,
                               dim3(nblk), dim3(256), args, 0, stream);
}

// Round 3
// 72.451 us; speedup vs baseline: 2.1483x; 2.1483x over previous
//
#include <hip/hip_runtime.h>

// Two graph nodes:
//   1) hipMemsetAsync(d_ws, 0, 4)  -- zero the arrival counter only
//   2) one_kernel                  -- partials + last-block-done final reduce
//
// ws layout: [0] uint arrival counter; float4 partials at ws+4+4*b
//            (loss, trivial, pos_count, neg_count) per block. 512 blocks -> 8.2 KB.
// No other ws bytes are read before being written (re-poison safe).

#define NJ 16   // j-chunks per i-tile; grid = ceil(n/256) * NJ blocks

__global__ __launch_bounds__(256) void one_kernel(
        const float* __restrict__ pred,
        const int* __restrict__ target,
        float* __restrict__ ws,
        float* __restrict__ out, int n) {
    __shared__ __align__(16) float s_pj[256];
    int tid = threadIdx.x;
    int b   = blockIdx.x;
    int ib  = b >> 4;        // i-tile   (NJ == 16)
    int jc  = b & (NJ - 1);  // j-chunk
    int i   = ib * 256 + tid;

    // Branch-free pair semantics: non-pos/invalid i -> -1e30 (contributes 0),
    // non-neg/invalid j -> +1e30 (contributes 0). -1e30 - 1e30 = -2e30, no inf.
    float pi = -1e30f;
    float triv = 0.0f, posf = 0.0f, negf = 0.0f;
    if (i < n) {
        float p = pred[i];
        int   t = target[i];
        if (t == 1) pi = p;
        if (jc == 0) {                        // each i counted exactly once
            triv = 1.0f / (p * p + 1e-5f);
            posf = (t == 1) ? 1.0f : 0.0f;
            negf = (t == 0) ? 1.0f : 0.0f;
        }
    }

    int jchunk = (n + NJ - 1) / NJ;
    int j0 = jc * jchunk;
    int j1 = min(j0 + jchunk, n);

    float a0 = 0.0f, a1 = 0.0f, a2 = 0.0f, a3 = 0.0f;
    for (int jb = j0; jb < j1; jb += 256) {
        int j = jb + tid;
        float pj = 1e30f;
        if (j < j1 && target[j] == 0) pj = pred[j];
        __syncthreads();            // protect previous iteration's readers
        s_pj[tid] = pj;
        __syncthreads();
        int cnt = min(256, j1 - jb);
        int c4  = cnt >> 2;
        const float4* s4 = (const float4*)s_pj;
        #pragma unroll 8
        for (int k = 0; k < c4; ++k) {
            float4 v = s4[k];       // LDS broadcast read, 16B per ds_read
            a0 += fmaxf(pi - v.x, 0.0f);
            a1 += fmaxf(pi - v.y, 0.0f);
            a2 += fmaxf(pi - v.z, 0.0f);
            a3 += fmaxf(pi - v.w, 0.0f);
        }
        for (int k = c4 << 2; k < cnt; ++k)
            a0 += fmaxf(pi - s_pj[k], 0.0f);
    }
    float acc = (a0 + a1) + (a2 + a3);

    // block reduce (wave64 shuffle + LDS across 4 waves)
    for (int off = 32; off > 0; off >>= 1) {
        acc  += __shfl_down(acc,  off, 64);
        triv += __shfl_down(triv, off, 64);
        posf += __shfl_down(posf, off, 64);
        negf += __shfl_down(negf, off, 64);
    }
    __shared__ float s_a[4], s_t[4], s_p[4], s_n[4];
    int lane = tid & 63, wave = tid >> 6;
    if (lane == 0) { s_a[wave] = acc; s_t[wave] = triv; s_p[wave] = posf; s_n[wave] = negf; }
    __syncthreads();

    __shared__ int is_last;
    if (tid == 0) {
        float4 part;
        part.x = s_a[0] + s_a[1] + s_a[2] + s_a[3];   // partial loss
        part.y = s_t[0] + s_t[1] + s_t[2] + s_t[3];   // partial trivial
        part.z = s_p[0] + s_p[1] + s_p[2] + s_p[3];   // partial pos count
        part.w = s_n[0] + s_n[1] + s_n[2] + s_n[3];   // partial neg count
        *(float4*)(ws + 4 + 4 * b) = part;
        __threadfence();                               // release partials
        unsigned old = atomicAdd((unsigned*)ws, 1u);   // device-scope (m20)
        is_last = (old == (unsigned)gridDim.x - 1u) ? 1 : 0;
    }
    __syncthreads();
    if (!is_last) return;
    __threadfence();                                   // acquire all partials

    // ---- final phase: only the last-arriving block ----
    int nblk = gridDim.x;
    float loss = 0.0f, tr = 0.0f, P = 0.0f, G = 0.0f;
    for (int k = tid; k < nblk; k += 256) {            // 2 float4 loads/thread
        float4 v = *(const float4*)(ws + 4 + 4 * k);
        loss += v.x; tr += v.y; P += v.z; G += v.w;
    }
    for (int off = 32; off > 0; off >>= 1) {
        loss += __shfl_down(loss, off, 64);
        tr   += __shfl_down(tr,   off, 64);
        P    += __shfl_down(P,    off, 64);
        G    += __shfl_down(G,    off, 64);
    }
    __syncthreads();                                   // s_* arrays reused
    if (lane == 0) { s_a[wave] = loss; s_t[wave] = tr; s_p[wave] = P; s_n[wave] = G; }
    __syncthreads();
    if (tid == 0) {
        float L  = s_a[0] + s_a[1] + s_a[2] + s_a[3];
        float T  = s_t[0] + s_t[1] + s_t[2] + s_t[3];
        float Pp = s_p[0] + s_p[1] + s_p[2] + s_p[3];
        float Gg = s_n[0] + s_n[1] + s_n[2] + s_n[3];
        out[0] = T / (float)n + L / (Pp * Gg);
    }
}

extern "C" void kernel_launch(void* const* d_in, const int* in_sizes, int n_in,
                              void* d_out, int out_size, void* d_ws, size_t ws_size,
                              hipStream_t stream) {
    const float* pred   = (const float*)d_in[0];
    const int*   target = (const int*)d_in[1];
    int n = in_sizes[0];
    float* ws = (float*)d_ws;

    hipMemsetAsync(d_ws, 0, 4, stream);    // zero the arrival counter only

    int nti  = (n + 255) / 256;   // i-tiles (32 at n=8192)
    int nblk = nti * NJ;          // 512 blocks (2 per CU)

    one_kernel<<<nblk, 256, 0, stream>>>(pred, target, ws, (float*)d_out, n);
}

// Round 4
// 64.855 us; speedup vs baseline: 2.3999x; 1.1171x over previous
//
#include <hip/hip_runtime.h>

// SINGLE dispatch, zero workspace initialization (re-poison safe).
// Fence-free join: each block publishes (loss_bits<<32)|MAGIC as ONE 64-bit
// atomic word -> payload+flag share the word, so per-word atomicity gives
// cross-XCD visibility with no __threadfence (R3 showed 512 device fences
// cost ~7 us; R2 showed grid.sync costs ~85 us).
// Block 0 computes trivial/pos/neg centrally (overlapped with other blocks'
// pair work), polls the flags, reduces, writes out. Only block 0 waits ->
// deadlock-free under any dispatch order.
//
// ws usage: NBLK uint64 flag words (4 KB at n=8192). Poison cannot forge
// MAGIC in low32 (p ~ 2^-32 per word).

#define NJ 16                 // j-chunks per i-tile; grid = ceil(n/256) * NJ
#define MAGIC 0x9E3779B9u     // flag in low32; loss payload in high32

typedef unsigned long long ull;

__global__ __launch_bounds__(256) void one_kernel(
        const float* __restrict__ pred,
        const int* __restrict__ target,
        ull* __restrict__ flags,          // = d_ws
        float* __restrict__ out, int n) {
    __shared__ __align__(16) float s_pj[256];
    int tid = threadIdx.x;
    int b   = blockIdx.x;
    int ib  = b >> 4;        // i-tile   (NJ == 16)
    int jc  = b & (NJ - 1);  // j-chunk
    int i   = ib * 256 + tid;

    // Branch-free pair semantics: non-pos/invalid i -> -1e30 (contributes 0),
    // non-neg/invalid j -> +1e30 (contributes 0). -1e30 - 1e30 = -2e30, no inf.
    float pi = -1e30f;
    if (i < n && target[i] == 1) pi = pred[i];

    int jchunk = (n + NJ - 1) / NJ;
    int j0 = jc * jchunk;
    int j1 = min(j0 + jchunk, n);

    float a0 = 0.0f, a1 = 0.0f, a2 = 0.0f, a3 = 0.0f;
    for (int jb = j0; jb < j1; jb += 256) {
        int j = jb + tid;
        float pj = 1e30f;
        if (j < j1 && target[j] == 0) pj = pred[j];
        __syncthreads();            // protect previous iteration's readers
        s_pj[tid] = pj;
        __syncthreads();
        int cnt = min(256, j1 - jb);
        int c4  = cnt >> 2;
        const float4* s4 = (const float4*)s_pj;
        #pragma unroll 8
        for (int k = 0; k < c4; ++k) {
            float4 v = s4[k];       // LDS broadcast read, 16B per ds_read
            a0 += fmaxf(pi - v.x, 0.0f);
            a1 += fmaxf(pi - v.y, 0.0f);
            a2 += fmaxf(pi - v.z, 0.0f);
            a3 += fmaxf(pi - v.w, 0.0f);
        }
        for (int k = c4 << 2; k < cnt; ++k)
            a0 += fmaxf(pi - s_pj[k], 0.0f);
    }
    float acc = (a0 + a1) + (a2 + a3);

    // block reduce (wave64 shuffle + LDS across 4 waves)
    for (int off = 32; off > 0; off >>= 1)
        acc += __shfl_down(acc, off, 64);
    __shared__ float s_a[4];
    int lane = tid & 63, wave = tid >> 6;
    if (lane == 0) s_a[wave] = acc;
    __syncthreads();
    if (tid == 0) {
        float part = s_a[0] + s_a[1] + s_a[2] + s_a[3];   // partial loss
        ull w = ((ull)__float_as_uint(part) << 32) | (ull)MAGIC;
        atomicExch(&flags[b], w);   // device-scope publish, payload+flag fused
    }
    if (b != 0) return;

    // ---- block 0 only: central stats (overlaps other blocks), join, final ----
    float triv = 0.0f; int pos = 0, neg = 0;
    for (int k = tid; k < n; k += 256) {      // 64 KB, cheap
        float p = pred[k];
        triv += 1.0f / (p * p + 1e-5f);
        int t = target[k];
        pos += (t == 1);
        neg += (t == 0);
    }

    int nblk = gridDim.x;
    float loss = 0.0f;
    for (int k = tid; k < nblk; k += 256) {   // poll 2 flags/thread
        ull v;
        do { v = atomicAdd(&flags[k], 0ULL); } while ((unsigned)v != MAGIC);
        loss += __uint_as_float((unsigned)(v >> 32));
    }

    for (int off = 32; off > 0; off >>= 1) {
        loss += __shfl_down(loss, off, 64);
        triv += __shfl_down(triv, off, 64);
        pos  += __shfl_down(pos,  off, 64);
        neg  += __shfl_down(neg,  off, 64);
    }
    __shared__ float s_l[4], s_t[4];
    __shared__ int   s_p[4], s_n[4];
    if (lane == 0) { s_l[wave] = loss; s_t[wave] = triv; s_p[wave] = pos; s_n[wave] = neg; }
    __syncthreads();
    if (tid == 0) {
        float L = s_l[0] + s_l[1] + s_l[2] + s_l[3];
        float T = s_t[0] + s_t[1] + s_t[2] + s_t[3];
        float P = (float)(s_p[0] + s_p[1] + s_p[2] + s_p[3]);
        float G = (float)(s_n[0] + s_n[1] + s_n[2] + s_n[3]);
        out[0] = T / (float)n + L / (P * G);
    }
}

extern "C" void kernel_launch(void* const* d_in, const int* in_sizes, int n_in,
                              void* d_out, int out_size, void* d_ws, size_t ws_size,
                              hipStream_t stream) {
    const float* pred   = (const float*)d_in[0];
    const int*   target = (const int*)d_in[1];
    int n = in_sizes[0];

    int nti  = (n + 255) / 256;   // i-tiles (32 at n=8192)
    int nblk = nti * NJ;          // 512 blocks (2 per CU -> all co-resident)

    one_kernel<<<nblk, 256, 0, stream>>>(pred, target, (ull*)d_ws,
                                         (float*)d_out, n);
}

// Round 5
// 60.368 us; speedup vs baseline: 2.5783x; 1.0743x over previous
//
#include <hip/hip_runtime.h>

// SINGLE dispatch, zero workspace init (re-poison safe).
// - 512 worker blocks: pair partials, publish (loss_bits<<32)|MAGIC via one
//   64-bit atomicExch (payload+flag share the word -> no __threadfence; R3
//   showed 512 device fences cost ~7us, R2 showed grid.sync costs ~85us).
// - block 0: dedicated join. Computes trivial/pos/neg (overlaps workers),
//   polls flags with s_sleep backoff, reduces, writes out[0].
// - LDS compaction: only actual negatives are staged (per-wave ordered
//   segments via ballot/popc, still 2 barriers/tile) -> inner pair work
//   halves vs sentinel scheme (sentinel j's contribute exactly 0.0 anyway).
//
// ws: 512 uint64 flag words (4 KB). Poison can't forge MAGIC (p ~ 2^-32).

#define NJ 16                 // j-chunks per i-tile
#define MAGIC 0x9E3779B9u     // flag in low32; loss payload bits in high32

typedef unsigned long long ull;

__global__ __launch_bounds__(256) void one_kernel(
        const float* __restrict__ pred,
        const int* __restrict__ target,
        ull* __restrict__ flags,          // = d_ws
        float* __restrict__ out, int n) {
    int tid  = threadIdx.x;
    int lane = tid & 63, wave = tid >> 6;

    if (blockIdx.x == 0) {
        // ---- dedicated join block: stats overlap workers, then poll ----
        float triv = 0.0f; int pos = 0, neg = 0;
        for (int k = tid; k < n; k += 256) {       // 64 KB, L2-resident
            float p = pred[k];
            triv += 1.0f / (p * p + 1e-5f);
            int t = target[k];
            pos += (t == 1);
            neg += (t == 0);
        }
        int nw = gridDim.x - 1;
        float loss = 0.0f;
        for (int k = tid; k < nw; k += 256) {      // 2 flags/thread
            ull v = atomicAdd(&flags[k], 0ULL);
            while ((unsigned)v != MAGIC) {
                __builtin_amdgcn_s_sleep(2);       // don't hammer the fabric
                v = atomicAdd(&flags[k], 0ULL);
            }
            loss += __uint_as_float((unsigned)(v >> 32));
        }
        for (int off = 32; off > 0; off >>= 1) {
            loss += __shfl_down(loss, off, 64);
            triv += __shfl_down(triv, off, 64);
            pos  += __shfl_down(pos,  off, 64);
            neg  += __shfl_down(neg,  off, 64);
        }
        __shared__ float s_l[4], s_t[4];
        __shared__ int   s_p[4], s_n[4];
        if (lane == 0) { s_l[wave] = loss; s_t[wave] = triv; s_p[wave] = pos; s_n[wave] = neg; }
        __syncthreads();
        if (tid == 0) {
            float L = s_l[0] + s_l[1] + s_l[2] + s_l[3];
            float T = s_t[0] + s_t[1] + s_t[2] + s_t[3];
            float P = (float)(s_p[0] + s_p[1] + s_p[2] + s_p[3]);
            float G = (float)(s_n[0] + s_n[1] + s_n[2] + s_n[3]);
            out[0] = T / (float)n + L / (P * G);
        }
        return;
    }

    // ---- worker block ----
    __shared__ __align__(16) float s_pj[256];      // 4 per-wave segments of 64
    __shared__ int s_wcnt[4];
    int wb = blockIdx.x - 1;
    int ib = wb >> 4;          // i-tile   (NJ == 16)
    int jc = wb & (NJ - 1);    // j-chunk
    int i  = ib * 256 + tid;

    // non-pos/invalid i -> pi = -1e30: relu(pi - pj) == 0 exactly for real pj
    float pi = -1e30f;
    if (i < n && target[i] == 1) pi = pred[i];

    int jchunk = (n + NJ - 1) / NJ;
    int j0 = jc * jchunk;
    int j1 = min(j0 + jchunk, n);

    float a0 = 0.0f, a1 = 0.0f, a2 = 0.0f, a3 = 0.0f;
    for (int jb = j0; jb < j1; jb += 256) {
        int j = jb + tid;
        bool f = false; float p = 0.0f;
        if (j < j1) { p = pred[j]; f = (target[j] == 0); }
        ull  m    = __ballot(f);
        int  rank = __popcll(m & ((1ull << lane) - 1ull));
        int  wcnt = __popcll(m);
        __syncthreads();               // protect previous iteration's readers
        if (f) s_pj[(wave << 6) + rank] = p;   // ordered within wave segment
        if (lane == 0) s_wcnt[wave] = wcnt;
        __syncthreads();
        #pragma unroll
        for (int w = 0; w < 4; ++w) {          // segments in j-order
            int cw = s_wcnt[w];
            const float*  seg = s_pj + (w << 6);
            const float4* s4  = (const float4*)seg;
            int c4 = cw >> 2;
            for (int k = 0; k < c4; ++k) {
                float4 v = s4[k];              // LDS broadcast read
                a0 += fmaxf(pi - v.x, 0.0f);
                a1 += fmaxf(pi - v.y, 0.0f);
                a2 += fmaxf(pi - v.z, 0.0f);
                a3 += fmaxf(pi - v.w, 0.0f);
            }
            for (int k = c4 << 2; k < cw; ++k)
                a0 += fmaxf(pi - seg[k], 0.0f);
        }
    }
    float acc = (a0 + a1) + (a2 + a3);

    for (int off = 32; off > 0; off >>= 1)
        acc += __shfl_down(acc, off, 64);
    __shared__ float s_a[4];
    if (lane == 0) s_a[wave] = acc;
    __syncthreads();
    if (tid == 0) {
        float part = s_a[0] + s_a[1] + s_a[2] + s_a[3];   // partial loss
        ull w = ((ull)__float_as_uint(part) << 32) | (ull)MAGIC;
        atomicExch(&flags[wb], w);     // device-scope publish, payload+flag
    }
}

extern "C" void kernel_launch(void* const* d_in, const int* in_sizes, int n_in,
                              void* d_out, int out_size, void* d_ws, size_t ws_size,
                              hipStream_t stream) {
    const float* pred   = (const float*)d_in[0];
    const int*   target = (const int*)d_in[1];
    int n = in_sizes[0];

    int nti  = (n + 255) / 256;        // i-tiles (32 at n=8192)
    int nblk = nti * NJ + 1;           // 512 workers + 1 join block

    one_kernel<<<nblk, 256, 0, stream>>>(pred, target, (ull*)d_ws,
                                         (float*)d_out, n);
}